// Round 1
// baseline (2056.246 us; speedup 1.0000x reference)
//
#include <hip/hip_runtime.h>

// Problem: MultiheadAttentionQ (S=2048, B=2, D=1024, H=16, hd=64), W8A8 fake-quant.
// Round 1: correctness-first fp32 pipeline. All quantized tensors are n*s with
// integer n in [-128,127] -> future rounds can use bf16/i8 MFMA exactly.

#define QMAX 127.0f

// absmax slots in ws (uint bits of fabsf)
#define SLOT_WI 0
#define SLOT_WO 1
#define SLOT_XQ 2
#define SLOT_XK 3
#define SLOT_XV 4
#define SLOT_HD 5
#define SLOT_Y  6
#define SLOT_Q  7

__global__ __launch_bounds__(256) void init_slots_k(unsigned* slots) {
  if (threadIdx.x < 16) slots[threadIdx.x] = 0u;
}

__global__ __launch_bounds__(256) void absmax_k(const float* __restrict__ x, int n4,
                                                unsigned* __restrict__ slots, int slot) {
  __shared__ float red[256];
  float lmax = 0.f;
  const float4* x4 = (const float4*)x;
  for (int i = blockIdx.x * 256 + threadIdx.x; i < n4; i += gridDim.x * 256) {
    float4 v = x4[i];
    lmax = fmaxf(lmax, fmaxf(fmaxf(fabsf(v.x), fabsf(v.y)), fmaxf(fabsf(v.z), fabsf(v.w))));
  }
  int tid = threadIdx.x;
  red[tid] = lmax; __syncthreads();
  for (int sh = 128; sh > 0; sh >>= 1) {
    if (tid < sh) red[tid] = fmaxf(red[tid], red[tid + sh]);
    __syncthreads();
  }
  if (tid == 0) atomicMax(&slots[slot], __float_as_uint(red[0]));
}

// out = clip(rint((in*premul)/s),-128,127)*s,  s = max(absmax(slot)*premul/127, 1e-8)
// optionally records absmax of the quantized OUTPUT into outAbsSlot.
__global__ __launch_bounds__(256) void quant_k(const float* __restrict__ in, float* __restrict__ out,
                                               int n4, unsigned* __restrict__ slots,
                                               int sSlot, int outAbsSlot, float premul) {
  __shared__ float red[256];
  float m = __uint_as_float(slots[sSlot]) * premul;
  float s = fmaxf(m / QMAX, 1e-8f);
  float lmax = 0.f;
  const float4* in4 = (const float4*)in;
  float4* out4 = (float4*)out;
  for (int i = blockIdx.x * 256 + threadIdx.x; i < n4; i += gridDim.x * 256) {
    float4 v = in4[i];
    float xs[4] = {v.x, v.y, v.z, v.w};
#pragma unroll
    for (int u = 0; u < 4; ++u) {
      float x = xs[u] * premul;
      float r = rintf(x / s);               // half-to-even, matches jnp.round
      r = fminf(fmaxf(r, -128.0f), 127.0f);
      xs[u] = r * s;
      lmax = fmaxf(lmax, fabsf(xs[u]));
    }
    out4[i] = make_float4(xs[0], xs[1], xs[2], xs[3]);
  }
  if (outAbsSlot >= 0) {
    int tid = threadIdx.x;
    red[tid] = lmax; __syncthreads();
    for (int sh = 128; sh > 0; sh >>= 1) {
      if (tid < sh) red[tid] = fmaxf(red[tid], red[tid + sh]);
      __syncthreads();
    }
    if (tid == 0) atomicMax(&slots[outAbsSlot], __float_as_uint(red[0]));
  }
}

// C = A(MxK) @ B(NxK)^T + bias(N). Records absmax(C) over ALL N columns into
// absSlot; stores only columns [colLo, colLo+colCount) to out (M x colCount).
// Tiles: 64x64x16, 256 threads, 4x4 micro-tile.
__global__ __launch_bounds__(256) void gemm_k(const float* __restrict__ A,
                                              const float* __restrict__ B,
                                              const float* __restrict__ bias,
                                              float* __restrict__ out,
                                              unsigned* __restrict__ slots,
                                              int K, int colLo, int colCount, int absSlot) {
  __shared__ float As[16][68];  // [k][m], pad 68 -> 272B rows keep float4 alignment
  __shared__ float Bs[16][68];  // [k][n]
  __shared__ float red[256];

  int tid = threadIdx.x;
  int tx = tid & 15, ty = tid >> 4;
  int m0 = blockIdx.y * 64, n0 = blockIdx.x * 64;

  int lrow = tid >> 2;           // 0..63
  int lcol = (tid & 3) << 2;     // 0,4,8,12

  const float* Aptr = A + (m0 + lrow) * K + lcol;
  const float* Bptr = B + (n0 + lrow) * K + lcol;

  float c[4][4] = {};

  for (int k0 = 0; k0 < K; k0 += 16) {
    float4 av = *(const float4*)(Aptr + k0);
    float4 bv = *(const float4*)(Bptr + k0);
    __syncthreads();
    As[lcol + 0][lrow] = av.x; As[lcol + 1][lrow] = av.y;
    As[lcol + 2][lrow] = av.z; As[lcol + 3][lrow] = av.w;
    Bs[lcol + 0][lrow] = bv.x; Bs[lcol + 1][lrow] = bv.y;
    Bs[lcol + 2][lrow] = bv.z; Bs[lcol + 3][lrow] = bv.w;
    __syncthreads();
#pragma unroll
    for (int kk = 0; kk < 16; ++kk) {
      float4 va = *(const float4*)&As[kk][ty * 4];
      float4 vb = *(const float4*)&Bs[kk][tx * 4];
      float a[4] = {va.x, va.y, va.z, va.w};
      float b[4] = {vb.x, vb.y, vb.z, vb.w};
#pragma unroll
      for (int i = 0; i < 4; ++i)
#pragma unroll
        for (int j = 0; j < 4; ++j) c[i][j] += a[i] * b[j];
    }
  }

  float lmax = 0.f;
#pragma unroll
  for (int i = 0; i < 4; ++i) {
    int gm = m0 + ty * 4 + i;
#pragma unroll
    for (int j = 0; j < 4; ++j) {
      int gn = n0 + tx * 4 + j;
      float v = c[i][j] + bias[gn];
      lmax = fmaxf(lmax, fabsf(v));
      if (gn >= colLo && gn < colLo + colCount)
        out[gm * colCount + (gn - colLo)] = v;
    }
  }
  red[tid] = lmax; __syncthreads();
  for (int sh = 128; sh > 0; sh >>= 1) {
    if (tid < sh) red[tid] = fmaxf(red[tid], red[tid + sh]);
    __syncthreads();
  }
  if (tid == 0) atomicMax(&slots[absSlot], __float_as_uint(red[0]));
}

// Flash-style attention. grid = (32 q-tiles, 32 batch-heads), 256 threads.
// q,k,v layout: elem (seq s, b, h, d) at ((s*2+b)*1024 + h*64 + d).
// K and V share one LDS buffer (keeps static LDS < 64 KB).
__global__ __launch_bounds__(256) void attn_k(const float* __restrict__ q,
                                              const float* __restrict__ k,
                                              const float* __restrict__ v,
                                              float* __restrict__ heads,
                                              unsigned* __restrict__ slots, int absSlot) {
  __shared__ float Qs[64][68];   // [d][qr]
  __shared__ float KVs[64][68];  // K phase: [d][kr]; V phase: [kr][d]
  __shared__ float Ss[64][68];   // [qr][kr] logits, then P
  __shared__ float mrow[64], lrow[64], arow[64];
  __shared__ float red[256];

  int tid = threadIdx.x;
  int tx = tid & 15, ty = tid >> 4;
  int bh = blockIdx.y;
  int b = bh >> 4, h = bh & 15;
  int q0 = blockIdx.x * 64;

  // load Q tile transposed
  for (int l = tid * 4; l < 64 * 64; l += 1024) {
    int row = l >> 6, d0 = l & 63;
    float4 val = *(const float4*)(q + ((q0 + row) * 2 + b) * 1024 + h * 64 + d0);
    Qs[d0 + 0][row] = val.x; Qs[d0 + 1][row] = val.y;
    Qs[d0 + 2][row] = val.z; Qs[d0 + 3][row] = val.w;
  }
  if (tid < 64) { mrow[tid] = -INFINITY; lrow[tid] = 0.f; }
  float o[4][4] = {};
  __syncthreads();

  for (int kt = 0; kt < 2048; kt += 64) {
    // K tile, transposed [d][kr]
    for (int l = tid * 4; l < 64 * 64; l += 1024) {
      int row = l >> 6, d0 = l & 63;
      float4 kv = *(const float4*)(k + ((kt + row) * 2 + b) * 1024 + h * 64 + d0);
      KVs[d0 + 0][row] = kv.x; KVs[d0 + 1][row] = kv.y;
      KVs[d0 + 2][row] = kv.z; KVs[d0 + 3][row] = kv.w;
    }
    __syncthreads();
    // S = Q K^T
    float s4[4][4] = {};
#pragma unroll 8
    for (int d = 0; d < 64; ++d) {
      float4 va = *(const float4*)&Qs[d][ty * 4];
      float4 vb = *(const float4*)&KVs[d][tx * 4];
      float a[4] = {va.x, va.y, va.z, va.w};
      float bb[4] = {vb.x, vb.y, vb.z, vb.w};
#pragma unroll
      for (int i = 0; i < 4; ++i)
#pragma unroll
        for (int j = 0; j < 4; ++j) s4[i][j] += a[i] * bb[j];
    }
#pragma unroll
    for (int i = 0; i < 4; ++i)
      *(float4*)&Ss[ty * 4 + i][tx * 4] = make_float4(s4[i][0], s4[i][1], s4[i][2], s4[i][3]);
    __syncthreads();  // Ss visible, everyone done with KVs(K)

    // V tile, natural [kr][d]
    for (int l = tid * 4; l < 64 * 64; l += 1024) {
      int row = l >> 6, d0 = l & 63;
      float4 vv = *(const float4*)(v + ((kt + row) * 2 + b) * 1024 + h * 64 + d0);
      *(float4*)&KVs[row][d0] = vv;
    }
    // online softmax, one thread per q row
    if (tid < 64) {
      int r = tid;
      float mold = mrow[r];
      float rmax = -INFINITY;
      for (int kk = 0; kk < 64; ++kk) rmax = fmaxf(rmax, Ss[r][kk]);
      float mnew = fmaxf(mold, rmax);
      float sum = 0.f;
      for (int kk = 0; kk < 64; ++kk) {
        float p = expf(Ss[r][kk] - mnew);
        Ss[r][kk] = p;
        sum += p;
      }
      float alpha = expf(mold - mnew);  // first tile: expf(-inf)=0
      arow[r] = alpha;
      mrow[r] = mnew;
      lrow[r] = lrow[r] * alpha + sum;
    }
    __syncthreads();

    // O = O*alpha + P @ V
    float av[4];
#pragma unroll
    for (int i = 0; i < 4; ++i) av[i] = arow[ty * 4 + i];
#pragma unroll
    for (int i = 0; i < 4; ++i)
#pragma unroll
      for (int j = 0; j < 4; ++j) o[i][j] *= av[i];
#pragma unroll 8
    for (int kk = 0; kk < 64; ++kk) {
      float p[4];
#pragma unroll
      for (int i = 0; i < 4; ++i) p[i] = Ss[ty * 4 + i][kk];
      float4 vb = *(const float4*)&KVs[kk][tx * 4];
      float bb[4] = {vb.x, vb.y, vb.z, vb.w};
#pragma unroll
      for (int i = 0; i < 4; ++i)
#pragma unroll
        for (int j = 0; j < 4; ++j) o[i][j] += p[i] * bb[j];
    }
    __syncthreads();  // before next K overwrite of KVs/Ss
  }

  float lmax = 0.f;
#pragma unroll
  for (int i = 0; i < 4; ++i) {
    float li = lrow[ty * 4 + i];
#pragma unroll
    for (int j = 0; j < 4; ++j) {
      float hv = o[i][j] / li;
      heads[((q0 + ty * 4 + i) * 2 + b) * 1024 + h * 64 + tx * 4 + j] = hv;
      lmax = fmaxf(lmax, fabsf(hv));
    }
  }
  red[tid] = lmax; __syncthreads();
  for (int sh = 128; sh > 0; sh >>= 1) {
    if (tid < sh) red[tid] = fmaxf(red[tid], red[tid + sh]);
    __syncthreads();
  }
  if (tid == 0) atomicMax(&slots[absSlot], __float_as_uint(red[0]));
}

extern "C" void kernel_launch(void* const* d_in, const int* in_sizes, int n_in,
                              void* d_out, int out_size, void* d_ws, size_t ws_size,
                              hipStream_t stream) {
  (void)in_sizes; (void)n_in; (void)out_size; (void)ws_size;
  const float* query = (const float*)d_in[0];
  const float* key   = (const float*)d_in[1];
  const float* value = (const float*)d_in[2];
  const float* Wi    = (const float*)d_in[3];
  const float* bi    = (const float*)d_in[4];
  const float* Wo    = (const float*)d_in[5];
  const float* bo    = (const float*)d_in[6];
  float* out = (float*)d_out;

  unsigned* slots = (unsigned*)d_ws;
  float* base = (float*)((char*)d_ws + 256);
  float* Wiq = base;                 // 3072*1024
  float* Woq = Wiq + 3145728;        // 1024*1024
  float* Xq  = Woq + 1048576;        // 4096*1024  (-> Q -> q; later aliased as Y)
  float* Xk  = Xq + 4194304;         // 4096*1024  (-> K)
  float* Xv  = Xk + 4194304;         // 4096*1024  (-> V)
  float* Hd  = Xv + 4194304;         // 4096*1024  heads
  float* Y   = Xq;                   // alias: q is dead after attention

  init_slots_k<<<1, 256, 0, stream>>>(slots);

  absmax_k<<<1024, 256, 0, stream>>>(Wi, 3145728 / 4, slots, SLOT_WI);
  absmax_k<<<512, 256, 0, stream>>>(Wo, 1048576 / 4, slots, SLOT_WO);
  quant_k<<<1024, 256, 0, stream>>>(Wi, Wiq, 3145728 / 4, slots, SLOT_WI, -1, 1.0f);
  quant_k<<<512, 256, 0, stream>>>(Wo, Woq, 1048576 / 4, slots, SLOT_WO, -1, 1.0f);

  // X_t = input @ Wi_q^T + bi ; absmax over full 3072 cols, store needed slice
  dim3 g1(48, 64);
  gemm_k<<<g1, 256, 0, stream>>>(query, Wiq, bi, Xq, slots, 1024, 0,    1024, SLOT_XQ);
  gemm_k<<<g1, 256, 0, stream>>>(key,   Wiq, bi, Xk, slots, 1024, 1024, 1024, SLOT_XK);
  gemm_k<<<g1, 256, 0, stream>>>(value, Wiq, bi, Xv, slots, 1024, 2048, 1024, SLOT_XV);

  // quantize slices (in place). Q also records absmax(Q) for the /8 re-quant.
  quant_k<<<2048, 256, 0, stream>>>(Xq, Xq, 1048576, slots, SLOT_XQ, SLOT_Q, 1.0f);
  quant_k<<<2048, 256, 0, stream>>>(Xk, Xk, 1048576, slots, SLOT_XK, -1, 1.0f);
  quant_k<<<2048, 256, 0, stream>>>(Xv, Xv, 1048576, slots, SLOT_XV, -1, 1.0f);
  // q = fake_quant(Q/8): scale = max(absmax(Q)/8/127, 1e-8), both /8 exact
  quant_k<<<2048, 256, 0, stream>>>(Xq, Xq, 1048576, slots, SLOT_Q, -1, 0.125f);

  dim3 ga(32, 32);
  attn_k<<<ga, 256, 0, stream>>>(Xq, Xk, Xv, Hd, slots, SLOT_HD);

  quant_k<<<2048, 256, 0, stream>>>(Hd, Hd, 1048576, slots, SLOT_HD, -1, 1.0f);

  dim3 g2(16, 64);
  gemm_k<<<g2, 256, 0, stream>>>(Hd, Woq, bo, Y, slots, 1024, 0, 1024, SLOT_Y);

  quant_k<<<2048, 256, 0, stream>>>(Y, out, 1048576, slots, SLOT_Y, -1, 1.0f);
}

// Round 2
// 607.644 us; speedup vs baseline: 3.3840x; 3.3840x over previous
//
#include <hip/hip_runtime.h>
#include <math.h>

// MultiheadAttentionQ: W8A8 fake-quant MHA. S=2048, B=2, D=1024, H=16, hd=64.
// R2: full f16-MFMA pipeline. Quantized tensors stored as integer n in f16
// (exact); unquantized GEMM inputs and softmax P use hi/lo f16 splits (exact
// to ~2^-23). Scales applied in fp32 epilogues.

typedef _Float16 f16;
typedef _Float16 half8 __attribute__((ext_vector_type(8)));
typedef _Float16 half4 __attribute__((ext_vector_type(4)));
typedef float floatx4 __attribute__((ext_vector_type(4)));

#define QMAX 127.0f

#define SLOT_WI 0
#define SLOT_WO 1
#define SLOT_XQ 2
#define SLOT_XK 3
#define SLOT_XV 4
#define SLOT_HD 5
#define SLOT_Y  6
#define SLOT_Q  7

__device__ __forceinline__ float slot_scale(const unsigned* slots, int slot, float premul) {
  if (slot < 0) return 1.0f;
  return fmaxf(__uint_as_float(slots[slot]) * premul / QMAX, 1e-8f);
}

__global__ __launch_bounds__(64) void init_slots_k(unsigned* slots) {
  if (threadIdx.x < 16) slots[threadIdx.x] = 0u;
}

__global__ __launch_bounds__(256) void absmax_k(const float* __restrict__ x, int n4,
                                                unsigned* __restrict__ slots, int slot) {
  __shared__ float red[256];
  float lmax = 0.f;
  const float4* x4 = (const float4*)x;
  for (int i = blockIdx.x * 256 + threadIdx.x; i < n4; i += gridDim.x * 256) {
    float4 v = x4[i];
    lmax = fmaxf(lmax, fmaxf(fmaxf(fabsf(v.x), fabsf(v.y)), fmaxf(fabsf(v.z), fabsf(v.w))));
  }
  int tid = threadIdx.x;
  red[tid] = lmax; __syncthreads();
  for (int sh = 128; sh > 0; sh >>= 1) {
    if (tid < sh) red[tid] = fmaxf(red[tid], red[tid + sh]);
    __syncthreads();
  }
  if (tid == 0) atomicMax(&slots[slot], __float_as_uint(red[0]));
}

// fp32 -> fp32 fake-quant (n*s). Optionally records absmax of quantized output.
__global__ __launch_bounds__(256) void quantf_k(const float* __restrict__ in, float* __restrict__ out,
                                                int n4, unsigned* __restrict__ slots,
                                                int sSlot, int outAbsSlot, float premul) {
  __shared__ float red[256];
  float s = slot_scale(slots, sSlot, premul);
  float lmax = 0.f;
  const float4* in4 = (const float4*)in;
  float4* out4 = (float4*)out;
  for (int i = blockIdx.x * 256 + threadIdx.x; i < n4; i += gridDim.x * 256) {
    float4 v = in4[i];
    float xs[4] = {v.x, v.y, v.z, v.w};
#pragma unroll
    for (int u = 0; u < 4; ++u) {
      float r = rintf((xs[u] * premul) / s);
      r = fminf(fmaxf(r, -128.0f), 127.0f);
      xs[u] = r * s;
      lmax = fmaxf(lmax, fabsf(xs[u]));
    }
    out4[i] = make_float4(xs[0], xs[1], xs[2], xs[3]);
  }
  if (outAbsSlot >= 0) {
    int tid = threadIdx.x;
    red[tid] = lmax; __syncthreads();
    for (int sh = 128; sh > 0; sh >>= 1) {
      if (tid < sh) red[tid] = fmaxf(red[tid], red[tid + sh]);
      __syncthreads();
    }
    if (tid == 0) atomicMax(&slots[outAbsSlot], __float_as_uint(red[0]));
  }
}

// fp32 -> f16 integer code n = clip(rint((x*premul)/s), -128, 127). Exact in f16.
__global__ __launch_bounds__(256) void quanti_k(const float* __restrict__ in, f16* __restrict__ out,
                                                int n4, const unsigned* __restrict__ slots,
                                                int sSlot, float premul) {
  float s = slot_scale(slots, sSlot, premul);
  const float4* in4 = (const float4*)in;
  for (int i = blockIdx.x * 256 + threadIdx.x; i < n4; i += gridDim.x * 256) {
    float4 v = in4[i];
    float xs[4] = {v.x, v.y, v.z, v.w};
    half4 o;
#pragma unroll
    for (int u = 0; u < 4; ++u) {
      float r = rintf((xs[u] * premul) / s);
      r = fminf(fmaxf(r, -128.0f), 127.0f);
      o[u] = (f16)r;
    }
    *(half4*)(out + (size_t)i * 4) = o;
  }
}

// fp32 -> hi/lo f16 split: x = hi + lo with ~2^-23 relative error.
__global__ __launch_bounds__(256) void split_k(const float* __restrict__ in,
                                               f16* __restrict__ hi, f16* __restrict__ lo, int n4) {
  const float4* in4 = (const float4*)in;
  for (int i = blockIdx.x * 256 + threadIdx.x; i < n4; i += gridDim.x * 256) {
    float4 v = in4[i];
    float xs[4] = {v.x, v.y, v.z, v.w};
    half4 h, l;
#pragma unroll
    for (int u = 0; u < 4; ++u) {
      f16 hv = (f16)xs[u];
      h[u] = hv;
      l[u] = (f16)(xs[u] - (float)hv);
    }
    *(half4*)(hi + (size_t)i * 4) = h;
    *(half4*)(lo + (size_t)i * 4) = l;
  }
}

// MFMA GEMM: C = (A0 + A1) @ B^T * (sA*sB) + bias. A: Mx K f16, B: N x K f16.
// 128x128 tile, 4 waves, 4x4 16x16 fragment tiles/wave, BK=32.
// Records absmax(C) over all N columns; stores columns [colLo, colLo+colCount).
__global__ __launch_bounds__(256) void gemm_mfma_k(const f16* __restrict__ A0,
                                                   const f16* __restrict__ A1,
                                                   const f16* __restrict__ B,
                                                   const float* __restrict__ bias,
                                                   float* __restrict__ out,
                                                   unsigned* __restrict__ slots,
                                                   int slotA, int slotB, int absSlot,
                                                   int K, int colLo, int colCount) {
  __shared__ f16 As[128][40];  // +8 halfs pad: 80B row stride, 2-way banks (free)
  __shared__ f16 Bs[128][40];
  __shared__ float red[256];

  int tid = threadIdx.x;
  int lane = tid & 63, w = tid >> 6;
  int wm = w >> 1, wn = w & 1;
  int quad = lane >> 4, l15 = lane & 15;
  int m0 = blockIdx.y * 128, n0 = blockIdx.x * 128;

  floatx4 acc[4][4];
#pragma unroll
  for (int i = 0; i < 4; ++i)
#pragma unroll
    for (int j = 0; j < 4; ++j) acc[i][j] = (floatx4){0.f, 0.f, 0.f, 0.f};

  int phases = (A1 != nullptr) ? 2 : 1;
  for (int ph = 0; ph < phases; ++ph) {
    const f16* A = ph ? A1 : A0;
    for (int k0 = 0; k0 < K; k0 += 32) {
      __syncthreads();
#pragma unroll
      for (int it = 0; it < 2; ++it) {
        int s = tid + it * 256;
        int row = s >> 2, seg = s & 3;
        *(half8*)&As[row][seg * 8] = *(const half8*)(A + (size_t)(m0 + row) * K + k0 + seg * 8);
        *(half8*)&Bs[row][seg * 8] = *(const half8*)(B + (size_t)(n0 + row) * K + k0 + seg * 8);
      }
      __syncthreads();
      half8 af[4], bf[4];
#pragma unroll
      for (int i = 0; i < 4; ++i) af[i] = *(half8*)&As[wm * 64 + i * 16 + l15][quad * 8];
#pragma unroll
      for (int j = 0; j < 4; ++j) bf[j] = *(half8*)&Bs[wn * 64 + j * 16 + l15][quad * 8];
#pragma unroll
      for (int i = 0; i < 4; ++i)
#pragma unroll
        for (int j = 0; j < 4; ++j)
          acc[i][j] = __builtin_amdgcn_mfma_f32_16x16x32_f16(af[i], bf[j], acc[i][j], 0, 0, 0);
    }
  }

  float sc = slot_scale(slots, slotA, 1.0f) * slot_scale(slots, slotB, 1.0f);
  float lmax = 0.f;
#pragma unroll
  for (int i = 0; i < 4; ++i) {
#pragma unroll
    for (int j = 0; j < 4; ++j) {
      int gn = n0 + wn * 64 + j * 16 + l15;
      float bv = bias[gn];
#pragma unroll
      for (int r = 0; r < 4; ++r) {
        int gm = m0 + wm * 64 + i * 16 + quad * 4 + r;
        float v = acc[i][j][r] * sc + bv;
        lmax = fmaxf(lmax, fabsf(v));
        if (gn >= colLo && gn < colLo + colCount)
          out[(size_t)gm * colCount + (gn - colLo)] = v;
      }
    }
  }
  red[tid] = lmax; __syncthreads();
  for (int sh = 128; sh > 0; sh >>= 1) {
    if (tid < sh) red[tid] = fmaxf(red[tid], red[tid + sh]);
    __syncthreads();
  }
  if (tid == 0) atomicMax(&slots[absSlot], __float_as_uint(red[0]));
}

// Transpose per-head V: Vint[(s*2+b)*1024 + h*64 + d] -> Vt[(bh*64+d)*2048 + s]
__global__ __launch_bounds__(256) void transpose_v_k(const f16* __restrict__ Vint,
                                                     f16* __restrict__ Vt) {
  __shared__ f16 T[64][72];
  int tid = threadIdx.x;
  int bh = blockIdx.y, b = bh >> 4, h = bh & 15;
  int k0 = blockIdx.x * 64;
#pragma unroll
  for (int it = 0; it < 2; ++it) {
    int s = tid + it * 256;
    int row = s >> 3, seg = s & 7;
    *(half8*)&T[row][seg * 8] =
        *(const half8*)(Vint + ((size_t)(k0 + row) * 2 + b) * 1024 + h * 64 + seg * 8);
  }
  __syncthreads();
#pragma unroll
  for (int it = 0; it < 2; ++it) {
    int s = tid + it * 256;
    int d = s >> 3, kseg = s & 7;
    half8 o;
#pragma unroll
    for (int j = 0; j < 8; ++j) o[j] = T[kseg * 8 + j][d];
    *(half8*)(Vt + ((size_t)bh * 64 + d) * 2048 + k0 + kseg * 8) = o;
  }
}

// Flash attention with f16 MFMA. Integer Q/K/V codes; S = int_acc * sq*sk.
// Block: 64 q-rows (4 waves x 16), K-tiles of 64, grid (32 qtiles, 32 bh).
__global__ __launch_bounds__(256) void attn_k(const f16* __restrict__ Qh,
                                              const f16* __restrict__ Kh,
                                              const f16* __restrict__ Vt,
                                              float* __restrict__ heads,
                                              unsigned* __restrict__ slots) {
  __shared__ f16 Ks[64][72];
  __shared__ f16 Vs[64][72];   // holds Vt tile: [d][k]
  __shared__ f16 Ph[4][16][72];
  __shared__ f16 Pl[4][16][72];
  __shared__ float red[256];

  int tid = threadIdx.x;
  int lane = tid & 63, w = tid >> 6;
  int quad = lane >> 4, l15 = lane & 15;
  int bh = blockIdx.y, b = bh >> 4, h = bh & 15;
  int q0 = blockIdx.x * 64;

  float sq = slot_scale(slots, SLOT_Q, 0.125f);
  float sk = slot_scale(slots, SLOT_XK, 1.0f);
  float sv = slot_scale(slots, SLOT_XV, 1.0f);
  float sS = sq * sk;

  // Q fragments (A-layout), loaded once: wave's q-rows = q0 + w*16 + l15
  const f16* qrow = Qh + ((size_t)(q0 + w * 16 + l15) * 2 + b) * 1024 + h * 64;
  half8 qf0 = *(const half8*)(qrow + quad * 8);
  half8 qf1 = *(const half8*)(qrow + 32 + quad * 8);

  floatx4 oacc[4];
#pragma unroll
  for (int j = 0; j < 4; ++j) oacc[j] = (floatx4){0.f, 0.f, 0.f, 0.f};
  float mrow[4] = {-INFINITY, -INFINITY, -INFINITY, -INFINITY};
  float lrow[4] = {0.f, 0.f, 0.f, 0.f};

  for (int kt = 0; kt < 2048; kt += 64) {
    __syncthreads();  // prev iter's PV reads done before restaging
#pragma unroll
    for (int it = 0; it < 2; ++it) {
      int s = tid + it * 256;
      int row = s >> 3, seg = s & 7;
      *(half8*)&Ks[row][seg * 8] =
          *(const half8*)(Kh + ((size_t)(kt + row) * 2 + b) * 1024 + h * 64 + seg * 8);
      *(half8*)&Vs[row][seg * 8] =
          *(const half8*)(Vt + ((size_t)bh * 64 + row) * 2048 + kt + seg * 8);
    }
    __syncthreads();

    // S = Q K^T (integer-exact)
    floatx4 sacc[4];
#pragma unroll
    for (int t = 0; t < 4; ++t) {
      sacc[t] = (floatx4){0.f, 0.f, 0.f, 0.f};
      half8 kf0 = *(half8*)&Ks[t * 16 + l15][quad * 8];
      half8 kf1 = *(half8*)&Ks[t * 16 + l15][32 + quad * 8];
      sacc[t] = __builtin_amdgcn_mfma_f32_16x16x32_f16(qf0, kf0, sacc[t], 0, 0, 0);
      sacc[t] = __builtin_amdgcn_mfma_f32_16x16x32_f16(qf1, kf1, sacc[t], 0, 0, 0);
    }

    // online softmax per q-row (row = quad*4 + r, shared by 16 lanes of quad)
    float p[4][4], alpha[4];
#pragma unroll
    for (int r = 0; r < 4; ++r) {
      float v0 = sacc[0][r] * sS, v1 = sacc[1][r] * sS;
      float v2 = sacc[2][r] * sS, v3 = sacc[3][r] * sS;
      float mx = fmaxf(fmaxf(v0, v1), fmaxf(v2, v3));
      mx = fmaxf(mx, __shfl_xor(mx, 1));
      mx = fmaxf(mx, __shfl_xor(mx, 2));
      mx = fmaxf(mx, __shfl_xor(mx, 4));
      mx = fmaxf(mx, __shfl_xor(mx, 8));
      float mnew = fmaxf(mrow[r], mx);
      float a = expf(mrow[r] - mnew);  // first tile: expf(-inf) = 0
      p[0][r] = expf(v0 - mnew); p[1][r] = expf(v1 - mnew);
      p[2][r] = expf(v2 - mnew); p[3][r] = expf(v3 - mnew);
      float sum = p[0][r] + p[1][r] + p[2][r] + p[3][r];
      sum += __shfl_xor(sum, 1);
      sum += __shfl_xor(sum, 2);
      sum += __shfl_xor(sum, 4);
      sum += __shfl_xor(sum, 8);
      lrow[r] = lrow[r] * a + sum;
      mrow[r] = mnew;
      alpha[r] = a;
    }
    // rescale O
#pragma unroll
    for (int j = 0; j < 4; ++j)
#pragma unroll
      for (int r = 0; r < 4; ++r) oacc[j][r] *= alpha[r];

    // P (C-layout) -> LDS (A-layout rows), hi/lo f16 split
#pragma unroll
    for (int t = 0; t < 4; ++t)
#pragma unroll
      for (int r = 0; r < 4; ++r) {
        float pv = p[t][r];
        f16 hi = (f16)pv;
        Ph[w][quad * 4 + r][t * 16 + l15] = hi;
        Pl[w][quad * 4 + r][t * 16 + l15] = (f16)(pv - (float)hi);
      }
    // own-wave LDS round-trip: no barrier needed (lgkmcnt orders it)
    half8 ph0 = *(half8*)&Ph[w][l15][quad * 8];
    half8 ph1 = *(half8*)&Ph[w][l15][32 + quad * 8];
    half8 pl0 = *(half8*)&Pl[w][l15][quad * 8];
    half8 pl1 = *(half8*)&Pl[w][l15][32 + quad * 8];
#pragma unroll
    for (int j = 0; j < 4; ++j) {
      half8 vf0 = *(half8*)&Vs[j * 16 + l15][quad * 8];
      half8 vf1 = *(half8*)&Vs[j * 16 + l15][32 + quad * 8];
      oacc[j] = __builtin_amdgcn_mfma_f32_16x16x32_f16(ph0, vf0, oacc[j], 0, 0, 0);
      oacc[j] = __builtin_amdgcn_mfma_f32_16x16x32_f16(ph1, vf1, oacc[j], 0, 0, 0);
      oacc[j] = __builtin_amdgcn_mfma_f32_16x16x32_f16(pl0, vf0, oacc[j], 0, 0, 0);
      oacc[j] = __builtin_amdgcn_mfma_f32_16x16x32_f16(pl1, vf1, oacc[j], 0, 0, 0);
    }
  }

  // epilogue: heads = O * sv / l
  float lmax = 0.f;
#pragma unroll
  for (int j = 0; j < 4; ++j)
#pragma unroll
    for (int r = 0; r < 4; ++r) {
      float hv = oacc[j][r] * sv / lrow[r];
      heads[((size_t)(q0 + w * 16 + quad * 4 + r) * 2 + b) * 1024 + h * 64 + j * 16 + l15] = hv;
      lmax = fmaxf(lmax, fabsf(hv));
    }
  red[tid] = lmax; __syncthreads();
  for (int sh = 128; sh > 0; sh >>= 1) {
    if (tid < sh) red[tid] = fmaxf(red[tid], red[tid + sh]);
    __syncthreads();
  }
  if (tid == 0) atomicMax(&slots[SLOT_HD], __float_as_uint(red[0]));
}

extern "C" void kernel_launch(void* const* d_in, const int* in_sizes, int n_in,
                              void* d_out, int out_size, void* d_ws, size_t ws_size,
                              hipStream_t stream) {
  (void)in_sizes; (void)n_in; (void)out_size; (void)ws_size;
  const float* query = (const float*)d_in[0];
  const float* key   = (const float*)d_in[1];
  const float* value = (const float*)d_in[2];
  const float* Wi    = (const float*)d_in[3];
  const float* bi    = (const float*)d_in[4];
  const float* Wo    = (const float*)d_in[5];
  const float* bo    = (const float*)d_in[6];
  float* out = (float*)d_out;

  // workspace layout (bytes, all 1KB-aligned)
  char* p = (char*)d_ws;
  unsigned* slots = (unsigned*)p;            p += 1024;
  f16* Wiq  = (f16*)p;                       p += 3072 * 1024 * 2;   // int codes
  f16* Woq  = (f16*)p;                       p += 1024 * 1024 * 2;
  f16* Ahi  = (f16*)p;                       p += 4096 * 1024 * 2;
  f16* Alo  = (f16*)p;                       p += 4096 * 1024 * 2;
  float* Hd = (float*)Ahi;                   // alias: splits dead after GEMM3
  float* Xq = (float*)p;                     p += 4096 * 1024 * 4;
  float* Y  = Xq;                            // alias: Xq dead after Qint made
  float* Xk = (float*)p;                     p += 4096 * 1024 * 4;
  f16* Vint = (f16*)Xk;                      // alias: Xk f32 dead after Kint
  float* Xv = (float*)p;                     p += 4096 * 1024 * 4;
  f16* Qint = (f16*)Xv;                      // alias first half: Xv dead after Vint
  f16* Hint = (f16*)(Xv + 2097152);          // alias second half
  f16* Kint = (f16*)p;                       p += 4096 * 1024 * 2;
  f16* Vt   = (f16*)p;                       p += 4096 * 1024 * 2;   // total ~92.3 MB

  init_slots_k<<<1, 64, 0, stream>>>(slots);

  absmax_k<<<1024, 256, 0, stream>>>(Wi, 786432, slots, SLOT_WI);
  absmax_k<<<512, 256, 0, stream>>>(Wo, 262144, slots, SLOT_WO);
  quanti_k<<<1024, 256, 0, stream>>>(Wi, Wiq, 786432, slots, SLOT_WI, 1.0f);
  quanti_k<<<512, 256, 0, stream>>>(Wo, Woq, 262144, slots, SLOT_WO, 1.0f);

  dim3 g1(24, 32);  // N=3072, M=4096
  split_k<<<1024, 256, 0, stream>>>(query, Ahi, Alo, 1048576);
  gemm_mfma_k<<<g1, 256, 0, stream>>>(Ahi, Alo, Wiq, bi, Xq, slots, -1, SLOT_WI, SLOT_XQ,
                                      1024, 0, 1024);
  split_k<<<1024, 256, 0, stream>>>(key, Ahi, Alo, 1048576);
  gemm_mfma_k<<<g1, 256, 0, stream>>>(Ahi, Alo, Wiq, bi, Xk, slots, -1, SLOT_WI, SLOT_XK,
                                      1024, 1024, 1024);
  split_k<<<1024, 256, 0, stream>>>(value, Ahi, Alo, 1048576);
  gemm_mfma_k<<<g1, 256, 0, stream>>>(Ahi, Alo, Wiq, bi, Xv, slots, -1, SLOT_WI, SLOT_XV,
                                      1024, 2048, 1024);

  // Q: fake_quant (fp32 out, records absmax(Q) for the /8 re-quant)
  quantf_k<<<1024, 256, 0, stream>>>(Xq, Xq, 1048576, slots, SLOT_XQ, SLOT_Q, 1.0f);
  quanti_k<<<1024, 256, 0, stream>>>(Xk, Kint, 1048576, slots, SLOT_XK, 1.0f);
  quanti_k<<<1024, 256, 0, stream>>>(Xv, Vint, 1048576, slots, SLOT_XV, 1.0f);
  // q = fake_quant(Q/8) -> integer codes
  quanti_k<<<1024, 256, 0, stream>>>(Xq, Qint, 1048576, slots, SLOT_Q, 0.125f);

  dim3 gt(32, 32);
  transpose_v_k<<<gt, 256, 0, stream>>>(Vint, Vt);

  dim3 ga(32, 32);
  attn_k<<<ga, 256, 0, stream>>>(Qint, Kint, Vt, Hd, slots);

  quanti_k<<<1024, 256, 0, stream>>>(Hd, Hint, 1048576, slots, SLOT_HD, 1.0f);

  dim3 g2(8, 32);  // N=1024, M=4096
  gemm_mfma_k<<<g2, 256, 0, stream>>>(Hint, nullptr, Woq, bo, Y, slots, SLOT_HD, SLOT_WO, SLOT_Y,
                                      1024, 0, 1024);

  quantf_k<<<1024, 256, 0, stream>>>(Y, out, 1048576, slots, SLOT_Y, -1, 1.0f);
}

// Round 3
// 520.008 us; speedup vs baseline: 3.9543x; 1.1685x over previous
//
#include <hip/hip_runtime.h>
#include <math.h>

// MultiheadAttentionQ: W8A8 fake-quant MHA. S=2048, B=2, D=1024, H=16, hd=64.
// R3: m97-style GEMMs (global_load_lds w16, fused hi/lo K-loop), attn with
// exp2-domain softmax, deferred l-reduction, swizzled unpadded K/V LDS.

typedef _Float16 f16;
typedef _Float16 half8 __attribute__((ext_vector_type(8)));
typedef _Float16 half4 __attribute__((ext_vector_type(4)));
typedef float floatx4 __attribute__((ext_vector_type(4)));

#define QMAX 127.0f

#define SLOT_WI 0
#define SLOT_WO 1
#define SLOT_XQ 2
#define SLOT_XK 3
#define SLOT_XV 4
#define SLOT_HD 5
#define SLOT_Y  6
#define SLOT_Q  7

__device__ __forceinline__ float slot_scale(const unsigned* slots, int slot, float premul) {
  if (slot < 0) return 1.0f;
  return fmaxf(__uint_as_float(slots[slot]) * premul / QMAX, 1e-8f);
}

// async global->LDS, 16B per lane; LDS dest = wave-uniform base + lane*16.
__device__ __forceinline__ void gl2lds16(const void* gsrc, void* ldst) {
  __builtin_amdgcn_global_load_lds((__attribute__((address_space(1))) void*)gsrc,
                                   (__attribute__((address_space(3))) void*)ldst, 16, 0, 0);
}

__device__ __forceinline__ half8 ld_p8(const f16* p) {
  half4 a = *(const half4*)p;
  half4 b = *(const half4*)(p + 4);
  half8 r;
#pragma unroll
  for (int i = 0; i < 4; ++i) { r[i] = a[i]; r[i + 4] = b[i]; }
  return r;
}

__global__ __launch_bounds__(64) void init_slots_k(unsigned* slots) {
  if (threadIdx.x < 16) slots[threadIdx.x] = 0u;
}

__global__ __launch_bounds__(256) void absmax_k(const float* __restrict__ x, int n4,
                                                unsigned* __restrict__ slots, int slot) {
  __shared__ float red[256];
  float lmax = 0.f;
  const float4* x4 = (const float4*)x;
  for (int i = blockIdx.x * 256 + threadIdx.x; i < n4; i += gridDim.x * 256) {
    float4 v = x4[i];
    lmax = fmaxf(lmax, fmaxf(fmaxf(fabsf(v.x), fabsf(v.y)), fmaxf(fabsf(v.z), fabsf(v.w))));
  }
  int tid = threadIdx.x;
  red[tid] = lmax; __syncthreads();
  for (int sh = 128; sh > 0; sh >>= 1) {
    if (tid < sh) red[tid] = fmaxf(red[tid], red[tid + sh]);
    __syncthreads();
  }
  if (tid == 0) atomicMax(&slots[slot], __float_as_uint(red[0]));
}

// fp32 -> fp32 fake-quant (n*s).
__global__ __launch_bounds__(256) void quantf_k(const float* __restrict__ in, float* __restrict__ out,
                                                int n4, unsigned* __restrict__ slots,
                                                int sSlot, float premul) {
  float s = slot_scale(slots, sSlot, premul);
  const float4* in4 = (const float4*)in;
  float4* out4 = (float4*)out;
  for (int i = blockIdx.x * 256 + threadIdx.x; i < n4; i += gridDim.x * 256) {
    float4 v = in4[i];
    float xs[4] = {v.x, v.y, v.z, v.w};
#pragma unroll
    for (int u = 0; u < 4; ++u) {
      float r = rintf((xs[u] * premul) / s);
      r = fminf(fmaxf(r, -128.0f), 127.0f);
      xs[u] = r * s;
    }
    out4[i] = make_float4(xs[0], xs[1], xs[2], xs[3]);
  }
}

// fp32 -> f16 integer codes. Optionally records absmax of quantized value
// (= s * max|code|, exact) into outAbsSlot.
__global__ __launch_bounds__(256) void quanti_k(const float* __restrict__ in, f16* __restrict__ out,
                                                int n4, unsigned* __restrict__ slots,
                                                int sSlot, int outAbsSlot, float premul) {
  __shared__ float red[256];
  float s = slot_scale(slots, sSlot, premul);
  float lmax = 0.f;
  const float4* in4 = (const float4*)in;
  for (int i = blockIdx.x * 256 + threadIdx.x; i < n4; i += gridDim.x * 256) {
    float4 v = in4[i];
    float xs[4] = {v.x, v.y, v.z, v.w};
    half4 o;
#pragma unroll
    for (int u = 0; u < 4; ++u) {
      float r = rintf((xs[u] * premul) / s);
      r = fminf(fmaxf(r, -128.0f), 127.0f);
      o[u] = (f16)r;
      lmax = fmaxf(lmax, fabsf(r));
    }
    *(half4*)(out + (size_t)i * 4) = o;
  }
  if (outAbsSlot >= 0) {
    int tid = threadIdx.x;
    red[tid] = lmax; __syncthreads();
    for (int sh = 128; sh > 0; sh >>= 1) {
      if (tid < sh) red[tid] = fmaxf(red[tid], red[tid + sh]);
      __syncthreads();
    }
    if (tid == 0) atomicMax(&slots[outAbsSlot], __float_as_uint(red[0] * s));
  }
}

// q = fake_quant(Q/8): codes' = clip(rint((c*s1*0.125)/s2)). Pure f16-code remap.
__global__ __launch_bounds__(256) void remapq_k(const f16* __restrict__ in, f16* __restrict__ out,
                                                int n8, const unsigned* __restrict__ slots) {
  float s1 = slot_scale(slots, SLOT_XQ, 1.0f);
  float s2 = slot_scale(slots, SLOT_Q, 0.125f);
  for (int i = blockIdx.x * 256 + threadIdx.x; i < n8; i += gridDim.x * 256) {
    half8 c = *(const half8*)(in + (size_t)i * 8);
    half8 o;
#pragma unroll
    for (int u = 0; u < 8; ++u) {
      float x = ((float)c[u] * s1) * 0.125f;
      float r = rintf(x / s2);
      o[u] = (f16)fminf(fmaxf(r, -128.0f), 127.0f);
    }
    *(half8*)(out + (size_t)i * 8) = o;
  }
}

// fp32 -> hi/lo f16 split.
__global__ __launch_bounds__(256) void split_k(const float* __restrict__ in,
                                               f16* __restrict__ hi, f16* __restrict__ lo, int n4) {
  const float4* in4 = (const float4*)in;
  for (int i = blockIdx.x * 256 + threadIdx.x; i < n4; i += gridDim.x * 256) {
    float4 v = in4[i];
    float xs[4] = {v.x, v.y, v.z, v.w};
    half4 h, l;
#pragma unroll
    for (int u = 0; u < 4; ++u) {
      f16 hv = (f16)xs[u];
      h[u] = hv;
      l[u] = (f16)(xs[u] - (float)hv);
    }
    *(half4*)(hi + (size_t)i * 4) = h;
    *(half4*)(lo + (size_t)i * 4) = l;
  }
}

// MFMA GEMM, m97-style staging. C = (A0[+A1]) @ B^T * (sA*sB) + bias.
// 128x128 tile, BK=32, unpadded LDS, global_load_lds w16.
template <bool HAS_LO>
__global__ __launch_bounds__(256) void gemm_mfma_k(const f16* __restrict__ A0,
                                                   const f16* __restrict__ A1,
                                                   const f16* __restrict__ B,
                                                   const float* __restrict__ bias,
                                                   float* __restrict__ out,
                                                   unsigned* __restrict__ slots,
                                                   int slotA, int slotB, int absSlot,
                                                   int K, int colLo, int colCount) {
  __shared__ f16 AsH[128 * 32];
  __shared__ f16 Bs[128 * 32];
  __shared__ f16 AsL[HAS_LO ? 128 * 32 : 64];
  __shared__ float red[256];

  int tid = threadIdx.x;
  int lane = tid & 63, w = tid >> 6;
  int wm = w >> 1, wn = w & 1;
  int quad = lane >> 4, l15 = lane & 15;
  int m0 = blockIdx.y * 128, n0 = blockIdx.x * 128;

  int srow = lane >> 2;        // row within a 16-row staging instr
  int sgr = (lane & 3) * 8;    // half offset within row

  floatx4 acc[4][4];
#pragma unroll
  for (int i = 0; i < 4; ++i)
#pragma unroll
    for (int j = 0; j < 4; ++j) acc[i][j] = (floatx4){0.f, 0.f, 0.f, 0.f};

  for (int k0 = 0; k0 < K; k0 += 32) {
    __syncthreads();
#pragma unroll
    for (int t = 0; t < 2; ++t) {
      int r0 = (w * 2 + t) * 16;
      gl2lds16(A0 + (size_t)(m0 + r0 + srow) * K + k0 + sgr, &AsH[r0 * 32]);
      gl2lds16(B + (size_t)(n0 + r0 + srow) * K + k0 + sgr, &Bs[r0 * 32]);
      if (HAS_LO)
        gl2lds16(A1 + (size_t)(m0 + r0 + srow) * K + k0 + sgr, &AsL[r0 * 32]);
    }
    __syncthreads();
    half8 ah[4], bfr[4], al[4];
#pragma unroll
    for (int i = 0; i < 4; ++i) ah[i] = *(half8*)&AsH[(wm * 64 + i * 16 + l15) * 32 + quad * 8];
#pragma unroll
    for (int j = 0; j < 4; ++j) bfr[j] = *(half8*)&Bs[(wn * 64 + j * 16 + l15) * 32 + quad * 8];
    if (HAS_LO) {
#pragma unroll
      for (int i = 0; i < 4; ++i) al[i] = *(half8*)&AsL[(wm * 64 + i * 16 + l15) * 32 + quad * 8];
    }
#pragma unroll
    for (int i = 0; i < 4; ++i)
#pragma unroll
      for (int j = 0; j < 4; ++j) {
        acc[i][j] = __builtin_amdgcn_mfma_f32_16x16x32_f16(ah[i], bfr[j], acc[i][j], 0, 0, 0);
        if (HAS_LO)
          acc[i][j] = __builtin_amdgcn_mfma_f32_16x16x32_f16(al[i], bfr[j], acc[i][j], 0, 0, 0);
      }
  }

  float sc = slot_scale(slots, slotA, 1.0f) * slot_scale(slots, slotB, 1.0f);
  float lmax = 0.f;
#pragma unroll
  for (int i = 0; i < 4; ++i) {
#pragma unroll
    for (int j = 0; j < 4; ++j) {
      int gn = n0 + wn * 64 + j * 16 + l15;
      float bv = bias[gn];
#pragma unroll
      for (int r = 0; r < 4; ++r) {
        int gm = m0 + wm * 64 + i * 16 + quad * 4 + r;
        float v = acc[i][j][r] * sc + bv;
        lmax = fmaxf(lmax, fabsf(v));
        if (gn >= colLo && gn < colLo + colCount)
          out[(size_t)gm * colCount + (gn - colLo)] = v;
      }
    }
  }
  red[tid] = lmax; __syncthreads();
  for (int sh = 128; sh > 0; sh >>= 1) {
    if (tid < sh) red[tid] = fmaxf(red[tid], red[tid + sh]);
    __syncthreads();
  }
  if (tid == 0) atomicMax(&slots[absSlot], __float_as_uint(red[0]));
}

// V transpose per head: Vint[(s*2+b)*1024 + h*64 + d] -> Vt[(bh*64+d)*2048 + s]
__global__ __launch_bounds__(256) void transpose_v_k(const f16* __restrict__ Vint,
                                                     f16* __restrict__ Vt) {
  __shared__ f16 T[64][72];
  int tid = threadIdx.x;
  int bh = blockIdx.y, b = bh >> 4, h = bh & 15;
  int k0 = blockIdx.x * 64;
#pragma unroll
  for (int it = 0; it < 2; ++it) {
    int s = tid + it * 256;
    int row = s >> 3, seg = s & 7;
    *(half8*)&T[row][seg * 8] =
        *(const half8*)(Vint + ((size_t)(k0 + row) * 2 + b) * 1024 + h * 64 + seg * 8);
  }
  __syncthreads();
#pragma unroll
  for (int it = 0; it < 2; ++it) {
    int s = tid + it * 256;
    int d = s >> 3, kseg = s & 7;
    half8 o;
#pragma unroll
    for (int j = 0; j < 8; ++j) o[j] = T[kseg * 8 + j][d];
    *(half8*)(Vt + ((size_t)bh * 64 + d) * 2048 + k0 + kseg * 8) = o;
  }
}

// Flash attention, f16 MFMA. exp2-domain online softmax, deferred l-reduce.
// K/V tiles: unpadded 64-half rows, XOR granule swizzle (g^=row&7) applied via
// global_load_lds per-lane source address.
__global__ __launch_bounds__(256) void attn_k(const f16* __restrict__ Qh,
                                              const f16* __restrict__ Kh,
                                              const f16* __restrict__ Vt,
                                              float* __restrict__ heads,
                                              unsigned* __restrict__ slots) {
  __shared__ f16 Ks[64 * 64];
  __shared__ f16 Vs[64 * 64];
  __shared__ f16 Ph[4][16][68];
  __shared__ f16 Pl[4][16][68];
  __shared__ float red[256];

  int tid = threadIdx.x;
  int lane = tid & 63, w = tid >> 6;
  int quad = lane >> 4, l15 = lane & 15;
  int bh = blockIdx.y, b = bh >> 4, h = bh & 15;
  int q0 = blockIdx.x * 64;

  float sq = slot_scale(slots, SLOT_Q, 0.125f);
  float sk = slot_scale(slots, SLOT_XK, 1.0f);
  float sv = slot_scale(slots, SLOT_XV, 1.0f);
  float cS = sq * sk * 1.44269504088896340736f;  // fold scale into log2 domain

  const f16* qrow = Qh + ((size_t)(q0 + w * 16 + l15) * 2 + b) * 1024 + h * 64;
  half8 qf0 = *(const half8*)(qrow + quad * 8);
  half8 qf1 = *(const half8*)(qrow + 32 + quad * 8);

  int srow = lane >> 3;  // row within 8-row staging instr
  int sp = lane & 7;     // LDS granule position

  floatx4 oacc[4];
#pragma unroll
  for (int j = 0; j < 4; ++j) oacc[j] = (floatx4){0.f, 0.f, 0.f, 0.f};
  float mrow[4] = {-INFINITY, -INFINITY, -INFINITY, -INFINITY};
  float lsum[4] = {0.f, 0.f, 0.f, 0.f};

  for (int kt = 0; kt < 2048; kt += 64) {
    __syncthreads();
#pragma unroll
    for (int t = 0; t < 2; ++t) {
      int r0 = (w * 2 + t) * 8;
      int row = r0 + srow;
      int g = sp ^ (row & 7);  // source granule for swizzled LDS position sp
      gl2lds16(Kh + ((size_t)(kt + row) * 2 + b) * 1024 + h * 64 + g * 8, &Ks[r0 * 64]);
      gl2lds16(Vt + ((size_t)bh * 64 + row) * 2048 + kt + g * 8, &Vs[r0 * 64]);
    }
    __syncthreads();

    // S = Q K^T (integer-exact)
    floatx4 sacc[4];
#pragma unroll
    for (int t = 0; t < 4; ++t) {
      int row = t * 16 + l15;
      int p1 = quad ^ (row & 7);
      half8 kf0 = *(half8*)&Ks[row * 64 + p1 * 8];
      half8 kf1 = *(half8*)&Ks[row * 64 + (p1 ^ 4) * 8];
      sacc[t] = (floatx4){0.f, 0.f, 0.f, 0.f};
      sacc[t] = __builtin_amdgcn_mfma_f32_16x16x32_f16(qf0, kf0, sacc[t], 0, 0, 0);
      sacc[t] = __builtin_amdgcn_mfma_f32_16x16x32_f16(qf1, kf1, sacc[t], 0, 0, 0);
    }

    // online softmax in exp2 domain; P -> LDS hi/lo
    float alpha[4];
#pragma unroll
    for (int r = 0; r < 4; ++r) {
      float y0 = sacc[0][r] * cS, y1 = sacc[1][r] * cS;
      float y2 = sacc[2][r] * cS, y3 = sacc[3][r] * cS;
      float mx = fmaxf(fmaxf(y0, y1), fmaxf(y2, y3));
      mx = fmaxf(mx, __shfl_xor(mx, 1));
      mx = fmaxf(mx, __shfl_xor(mx, 2));
      mx = fmaxf(mx, __shfl_xor(mx, 4));
      mx = fmaxf(mx, __shfl_xor(mx, 8));
      float mnew = fmaxf(mrow[r], mx);
      float a = __builtin_amdgcn_exp2f(mrow[r] - mnew);  // first tile: 0
      mrow[r] = mnew;
      float p0 = __builtin_amdgcn_exp2f(y0 - mnew);
      float p1 = __builtin_amdgcn_exp2f(y1 - mnew);
      float p2 = __builtin_amdgcn_exp2f(y2 - mnew);
      float p3 = __builtin_amdgcn_exp2f(y3 - mnew);
      lsum[r] = lsum[r] * a + (p0 + p1 + p2 + p3);  // per-lane partial; reduce at end
      alpha[r] = a;
      int pr = quad * 4 + r;
      f16 h0 = (f16)p0, h1 = (f16)p1, h2 = (f16)p2, h3 = (f16)p3;
      Ph[w][pr][l15] = h0;       Ph[w][pr][16 + l15] = h1;
      Ph[w][pr][32 + l15] = h2;  Ph[w][pr][48 + l15] = h3;
      Pl[w][pr][l15] = (f16)(p0 - (float)h0);
      Pl[w][pr][16 + l15] = (f16)(p1 - (float)h1);
      Pl[w][pr][32 + l15] = (f16)(p2 - (float)h2);
      Pl[w][pr][48 + l15] = (f16)(p3 - (float)h3);
    }
#pragma unroll
    for (int j = 0; j < 4; ++j)
#pragma unroll
      for (int r = 0; r < 4; ++r) oacc[j][r] *= alpha[r];

    // own-wave LDS round-trip (lgkmcnt orders it; no barrier needed)
    half8 ph0 = ld_p8(&Ph[w][l15][quad * 8]);
    half8 ph1 = ld_p8(&Ph[w][l15][32 + quad * 8]);
    half8 pl0 = ld_p8(&Pl[w][l15][quad * 8]);
    half8 pl1 = ld_p8(&Pl[w][l15][32 + quad * 8]);
#pragma unroll
    for (int j = 0; j < 4; ++j) {
      int row = j * 16 + l15;
      int p1 = quad ^ (row & 7);
      half8 vf0 = *(half8*)&Vs[row * 64 + p1 * 8];
      half8 vf1 = *(half8*)&Vs[row * 64 + (p1 ^ 4) * 8];
      oacc[j] = __builtin_amdgcn_mfma_f32_16x16x32_f16(ph0, vf0, oacc[j], 0, 0, 0);
      oacc[j] = __builtin_amdgcn_mfma_f32_16x16x32_f16(ph1, vf1, oacc[j], 0, 0, 0);
      oacc[j] = __builtin_amdgcn_mfma_f32_16x16x32_f16(pl0, vf0, oacc[j], 0, 0, 0);
      oacc[j] = __builtin_amdgcn_mfma_f32_16x16x32_f16(pl1, vf1, oacc[j], 0, 0, 0);
    }
  }

  // final l reduction across the 16 lanes of each quad
#pragma unroll
  for (int r = 0; r < 4; ++r) {
    float s = lsum[r];
    s += __shfl_xor(s, 1);
    s += __shfl_xor(s, 2);
    s += __shfl_xor(s, 4);
    s += __shfl_xor(s, 8);
    lsum[r] = s;
  }

  float lmax = 0.f;
#pragma unroll
  for (int j = 0; j < 4; ++j)
#pragma unroll
    for (int r = 0; r < 4; ++r) {
      float hv = oacc[j][r] * sv / lsum[r];
      heads[((size_t)(q0 + w * 16 + quad * 4 + r) * 2 + b) * 1024 + h * 64 + j * 16 + l15] = hv;
      lmax = fmaxf(lmax, fabsf(hv));
    }
  red[tid] = lmax; __syncthreads();
  for (int sh = 128; sh > 0; sh >>= 1) {
    if (tid < sh) red[tid] = fmaxf(red[tid], red[tid + sh]);
    __syncthreads();
  }
  if (tid == 0) atomicMax(&slots[SLOT_HD], __float_as_uint(red[0]));
}

extern "C" void kernel_launch(void* const* d_in, const int* in_sizes, int n_in,
                              void* d_out, int out_size, void* d_ws, size_t ws_size,
                              hipStream_t stream) {
  (void)in_sizes; (void)n_in; (void)out_size; (void)ws_size;
  const float* query = (const float*)d_in[0];
  const float* key   = (const float*)d_in[1];
  const float* value = (const float*)d_in[2];
  const float* Wi    = (const float*)d_in[3];
  const float* bi    = (const float*)d_in[4];
  const float* Wo    = (const float*)d_in[5];
  const float* bo    = (const float*)d_in[6];
  float* out = (float*)d_out;

  // workspace (~92.3 MB, matches R2 footprint)
  char* p = (char*)d_ws;
  unsigned* slots = (unsigned*)p;            p += 1024;
  f16* Wiq  = (f16*)p;                       p += 3072 * 1024 * 2;
  f16* Woq  = (f16*)p;                       p += 1024 * 1024 * 2;
  f16* Ahi  = (f16*)p;                       p += 4096 * 1024 * 2;
  f16* Alo  = (f16*)p;                       p += 4096 * 1024 * 2;
  float* Hd = (float*)Ahi;                   // alias (16.8 MB spans Ahi+Alo)
  f16* Vint = (f16*)Ahi;                     // alias: Ahi dead after GEMM3
  float* Xq = (float*)p;                     p += 4096 * 1024 * 4;
  float* Y  = Xq;                            // alias: Xq dead after Qc made
  float* Xk = (float*)p;                     p += 4096 * 1024 * 4;
  f16* Qc   = (f16*)Xk;                      // alias: Xk dead after Kint
  f16* Qint = (f16*)((char*)Xk + 4096 * 1024 * 2);
  float* Xv = (float*)p;                     p += 4096 * 1024 * 4;
  f16* Hint = (f16*)Xv;                      // alias: Xv dead after Vint
  f16* Kint = (f16*)p;                       p += 4096 * 1024 * 2;
  f16* Vt   = (f16*)p;                       p += 4096 * 1024 * 2;

  init_slots_k<<<1, 64, 0, stream>>>(slots);

  absmax_k<<<1024, 256, 0, stream>>>(Wi, 786432, slots, SLOT_WI);
  absmax_k<<<512, 256, 0, stream>>>(Wo, 262144, slots, SLOT_WO);
  quanti_k<<<1024, 256, 0, stream>>>(Wi, Wiq, 786432, slots, SLOT_WI, -1, 1.0f);
  quanti_k<<<512, 256, 0, stream>>>(Wo, Woq, 262144, slots, SLOT_WO, -1, 1.0f);

  dim3 g1(24, 32);  // N=3072, M=4096
  split_k<<<1024, 256, 0, stream>>>(query, Ahi, Alo, 1048576);
  gemm_mfma_k<true><<<g1, 256, 0, stream>>>(Ahi, Alo, Wiq, bi, Xq, slots, -1, SLOT_WI, SLOT_XQ,
                                            1024, 0, 1024);
  split_k<<<1024, 256, 0, stream>>>(key, Ahi, Alo, 1048576);
  gemm_mfma_k<true><<<g1, 256, 0, stream>>>(Ahi, Alo, Wiq, bi, Xk, slots, -1, SLOT_WI, SLOT_XK,
                                            1024, 1024, 1024);
  split_k<<<1024, 256, 0, stream>>>(value, Ahi, Alo, 1048576);
  gemm_mfma_k<true><<<g1, 256, 0, stream>>>(Ahi, Alo, Wiq, bi, Xv, slots, -1, SLOT_WI, SLOT_XV,
                                            1024, 2048, 1024);

  quanti_k<<<1024, 256, 0, stream>>>(Xk, Kint, 1048576, slots, SLOT_XK, -1, 1.0f);
  quanti_k<<<1024, 256, 0, stream>>>(Xv, Vint, 1048576, slots, SLOT_XV, -1, 1.0f);

  dim3 gt(32, 32);
  transpose_v_k<<<gt, 256, 0, stream>>>(Vint, Vt);

  // Q codes + absmax(Q)=s*max|code|, then /8 re-quant as pure code remap
  quanti_k<<<1024, 256, 0, stream>>>(Xq, Qc, 1048576, slots, SLOT_XQ, SLOT_Q, 1.0f);
  remapq_k<<<512, 256, 0, stream>>>(Qc, Qint, 524288, slots);

  dim3 ga(32, 32);
  attn_k<<<ga, 256, 0, stream>>>(Qint, Kint, Vt, Hd, slots);

  quanti_k<<<1024, 256, 0, stream>>>(Hd, Hint, 1048576, slots, SLOT_HD, -1, 1.0f);

  dim3 g2(8, 32);  // N=1024, M=4096
  gemm_mfma_k<false><<<g2, 256, 0, stream>>>(Hint, nullptr, Woq, bo, Y, slots,
                                             SLOT_HD, SLOT_WO, SLOT_Y, 1024, 0, 1024);

  quantf_k<<<1024, 256, 0, stream>>>(Y, out, 1048576, slots, SLOT_Y, 1.0f);
}

// Round 5
// 505.669 us; speedup vs baseline: 4.0664x; 1.0284x over previous
//
#include <hip/hip_runtime.h>
#include <math.h>

// MultiheadAttentionQ: W8A8 fake-quant MHA. S=2048, B=2, D=1024, H=16, hd=64.
// R5 = R4 with compile fix: cvt_pkrtz returns __fp16x2, bit_cast to _Float16x2.
// attn softmax VALU diet (fma-folded exp2 args, pkrtz-packed b32 P stores with
// k-permuted V layout, b128 P reads), fused V quant+transpose+permute.

typedef _Float16 f16;
typedef _Float16 half8 __attribute__((ext_vector_type(8)));
typedef _Float16 half4 __attribute__((ext_vector_type(4)));
typedef _Float16 half2v __attribute__((ext_vector_type(2)));
typedef __fp16 fp16x2 __attribute__((ext_vector_type(2)));
typedef float floatx4 __attribute__((ext_vector_type(4)));

#define QMAX 127.0f

#define SLOT_WI 0
#define SLOT_WO 1
#define SLOT_XQ 2
#define SLOT_XK 3
#define SLOT_XV 4
#define SLOT_HD 5
#define SLOT_Y  6
#define SLOT_Q  7

__device__ __forceinline__ float slot_scale(const unsigned* slots, int slot, float premul) {
  if (slot < 0) return 1.0f;
  return fmaxf(__uint_as_float(slots[slot]) * premul / QMAX, 1e-8f);
}

// async global->LDS, 16B per lane; LDS dest = wave-uniform base + lane*16.
__device__ __forceinline__ void gl2lds16(const void* gsrc, void* ldst) {
  __builtin_amdgcn_global_load_lds((__attribute__((address_space(1))) void*)gsrc,
                                   (__attribute__((address_space(3))) void*)ldst, 16, 0, 0);
}

__device__ __forceinline__ half2v pack2(float a, float b) {
  fp16x2 r = __builtin_amdgcn_cvt_pkrtz(a, b);
  return __builtin_bit_cast(half2v, r);
}

// k-permutation within a 64-k tile induced by packed P stores:
// position 2i <- k=i, 2i+1 <- k=16+i (per 32-block).
__device__ __forceinline__ int vperm(int pos) {
  int base = pos & 32;
  int p = pos & 31;
  return base + ((p & 1) ? 16 + (p >> 1) : (p >> 1));
}

__global__ __launch_bounds__(64) void init_slots_k(unsigned* slots) {
  if (threadIdx.x < 16) slots[threadIdx.x] = 0u;
}

__global__ __launch_bounds__(256) void absmax_k(const float* __restrict__ x, int n4,
                                                unsigned* __restrict__ slots, int slot) {
  __shared__ float red[256];
  float lmax = 0.f;
  const float4* x4 = (const float4*)x;
  for (int i = blockIdx.x * 256 + threadIdx.x; i < n4; i += gridDim.x * 256) {
    float4 v = x4[i];
    lmax = fmaxf(lmax, fmaxf(fmaxf(fabsf(v.x), fabsf(v.y)), fmaxf(fabsf(v.z), fabsf(v.w))));
  }
  int tid = threadIdx.x;
  red[tid] = lmax; __syncthreads();
  for (int sh = 128; sh > 0; sh >>= 1) {
    if (tid < sh) red[tid] = fmaxf(red[tid], red[tid + sh]);
    __syncthreads();
  }
  if (tid == 0) atomicMax(&slots[slot], __float_as_uint(red[0]));
}

// fp32 -> fp32 fake-quant (n*s).
__global__ __launch_bounds__(256) void quantf_k(const float* __restrict__ in, float* __restrict__ out,
                                                int n4, unsigned* __restrict__ slots,
                                                int sSlot, float premul) {
  float s = slot_scale(slots, sSlot, premul);
  const float4* in4 = (const float4*)in;
  float4* out4 = (float4*)out;
  for (int i = blockIdx.x * 256 + threadIdx.x; i < n4; i += gridDim.x * 256) {
    float4 v = in4[i];
    float xs[4] = {v.x, v.y, v.z, v.w};
#pragma unroll
    for (int u = 0; u < 4; ++u) {
      float r = rintf((xs[u] * premul) / s);
      r = fminf(fmaxf(r, -128.0f), 127.0f);
      xs[u] = r * s;
    }
    out4[i] = make_float4(xs[0], xs[1], xs[2], xs[3]);
  }
}

// fp32 -> f16 integer codes. Optionally records absmax of quantized value
// (= s * max|code|, exact) into outAbsSlot.
__global__ __launch_bounds__(256) void quanti_k(const float* __restrict__ in, f16* __restrict__ out,
                                                int n4, unsigned* __restrict__ slots,
                                                int sSlot, int outAbsSlot, float premul) {
  __shared__ float red[256];
  float s = slot_scale(slots, sSlot, premul);
  float lmax = 0.f;
  const float4* in4 = (const float4*)in;
  for (int i = blockIdx.x * 256 + threadIdx.x; i < n4; i += gridDim.x * 256) {
    float4 v = in4[i];
    float xs[4] = {v.x, v.y, v.z, v.w};
    half4 o;
#pragma unroll
    for (int u = 0; u < 4; ++u) {
      float r = rintf((xs[u] * premul) / s);
      r = fminf(fmaxf(r, -128.0f), 127.0f);
      o[u] = (f16)r;
      lmax = fmaxf(lmax, fabsf(r));
    }
    *(half4*)(out + (size_t)i * 4) = o;
  }
  if (outAbsSlot >= 0) {
    int tid = threadIdx.x;
    red[tid] = lmax; __syncthreads();
    for (int sh = 128; sh > 0; sh >>= 1) {
      if (tid < sh) red[tid] = fmaxf(red[tid], red[tid + sh]);
      __syncthreads();
    }
    if (tid == 0) atomicMax(&slots[outAbsSlot], __float_as_uint(red[0] * s));
  }
}

// q = fake_quant(Q/8): codes' = clip(rint((c*s1*0.125)/s2)). Pure f16-code remap.
__global__ __launch_bounds__(256) void remapq_k(const f16* __restrict__ in, f16* __restrict__ out,
                                                int n8, const unsigned* __restrict__ slots) {
  float s1 = slot_scale(slots, SLOT_XQ, 1.0f);
  float s2 = slot_scale(slots, SLOT_Q, 0.125f);
  for (int i = blockIdx.x * 256 + threadIdx.x; i < n8; i += gridDim.x * 256) {
    half8 c = *(const half8*)(in + (size_t)i * 8);
    half8 o;
#pragma unroll
    for (int u = 0; u < 8; ++u) {
      float x = ((float)c[u] * s1) * 0.125f;
      float r = rintf(x / s2);
      o[u] = (f16)fminf(fmaxf(r, -128.0f), 127.0f);
    }
    *(half8*)(out + (size_t)i * 8) = o;
  }
}

// fp32 -> hi/lo f16 split.
__global__ __launch_bounds__(256) void split_k(const float* __restrict__ in,
                                               f16* __restrict__ hi, f16* __restrict__ lo, int n4) {
  const float4* in4 = (const float4*)in;
  for (int i = blockIdx.x * 256 + threadIdx.x; i < n4; i += gridDim.x * 256) {
    float4 v = in4[i];
    float xs[4] = {v.x, v.y, v.z, v.w};
    half4 h, l;
#pragma unroll
    for (int u = 0; u < 4; ++u) {
      f16 hv = (f16)xs[u];
      h[u] = hv;
      l[u] = (f16)(xs[u] - (float)hv);
    }
    *(half4*)(hi + (size_t)i * 4) = h;
    *(half4*)(lo + (size_t)i * 4) = l;
  }
}

// Fused V: quantize Xv -> codes, transpose per head, apply vperm within each
// 64-k tile. Vt[(bh*64+d)*2048 + kt + pos] = code(V[k=kt+vperm(pos)][d]).
__global__ __launch_bounds__(256) void quantv_t_k(const float* __restrict__ Xv,
                                                  f16* __restrict__ Vt,
                                                  const unsigned* __restrict__ slots) {
  __shared__ f16 T[64][68];
  int tid = threadIdx.x;
  int bh = blockIdx.y, b = bh >> 4, h = bh & 15;
  int k0 = blockIdx.x * 64;
  float s = slot_scale(slots, SLOT_XV, 1.0f);
#pragma unroll
  for (int it = 0; it < 4; ++it) {
    int idx = tid + it * 256;            // 1024 float4 slots
    int row = idx >> 4, dseg = idx & 15;
    float4 v = *(const float4*)(Xv + ((size_t)(k0 + row) * 2 + b) * 1024 + h * 64 + dseg * 4);
    float xs[4] = {v.x, v.y, v.z, v.w};
    half4 o;
#pragma unroll
    for (int u = 0; u < 4; ++u) {
      float r = rintf(xs[u] / s);
      o[u] = (f16)fminf(fmaxf(r, -128.0f), 127.0f);
    }
    *(half4*)&T[row][dseg * 4] = o;
  }
  __syncthreads();
#pragma unroll
  for (int it = 0; it < 2; ++it) {
    int sdx = tid + it * 256;            // 512 half8 slots
    int d = sdx >> 3, j = sdx & 7;
    half8 o;
#pragma unroll
    for (int l = 0; l < 8; ++l) o[l] = T[vperm(j * 8 + l)][d];
    *(half8*)(Vt + ((size_t)bh * 64 + d) * 2048 + k0 + j * 8) = o;
  }
}

// MFMA GEMM, m97-style staging. C = (A0[+A1]) @ B^T * (sA*sB) + bias.
template <bool HAS_LO>
__global__ __launch_bounds__(256) void gemm_mfma_k(const f16* __restrict__ A0,
                                                   const f16* __restrict__ A1,
                                                   const f16* __restrict__ B,
                                                   const float* __restrict__ bias,
                                                   float* __restrict__ out,
                                                   unsigned* __restrict__ slots,
                                                   int slotA, int slotB, int absSlot,
                                                   int K, int colLo, int colCount) {
  __shared__ f16 AsH[128 * 32];
  __shared__ f16 Bs[128 * 32];
  __shared__ f16 AsL[HAS_LO ? 128 * 32 : 64];
  __shared__ float red[256];

  int tid = threadIdx.x;
  int lane = tid & 63, w = tid >> 6;
  int wm = w >> 1, wn = w & 1;
  int quad = lane >> 4, l15 = lane & 15;
  int m0 = blockIdx.y * 128, n0 = blockIdx.x * 128;

  int srow = lane >> 2;
  int sgr = (lane & 3) * 8;

  floatx4 acc[4][4];
#pragma unroll
  for (int i = 0; i < 4; ++i)
#pragma unroll
    for (int j = 0; j < 4; ++j) acc[i][j] = (floatx4){0.f, 0.f, 0.f, 0.f};

  for (int k0 = 0; k0 < K; k0 += 32) {
    __syncthreads();
#pragma unroll
    for (int t = 0; t < 2; ++t) {
      int r0 = (w * 2 + t) * 16;
      gl2lds16(A0 + (size_t)(m0 + r0 + srow) * K + k0 + sgr, &AsH[r0 * 32]);
      gl2lds16(B + (size_t)(n0 + r0 + srow) * K + k0 + sgr, &Bs[r0 * 32]);
      if (HAS_LO)
        gl2lds16(A1 + (size_t)(m0 + r0 + srow) * K + k0 + sgr, &AsL[r0 * 32]);
    }
    __syncthreads();
    half8 ah[4], bfr[4], al[4];
#pragma unroll
    for (int i = 0; i < 4; ++i) ah[i] = *(half8*)&AsH[(wm * 64 + i * 16 + l15) * 32 + quad * 8];
#pragma unroll
    for (int j = 0; j < 4; ++j) bfr[j] = *(half8*)&Bs[(wn * 64 + j * 16 + l15) * 32 + quad * 8];
    if (HAS_LO) {
#pragma unroll
      for (int i = 0; i < 4; ++i) al[i] = *(half8*)&AsL[(wm * 64 + i * 16 + l15) * 32 + quad * 8];
    }
#pragma unroll
    for (int i = 0; i < 4; ++i)
#pragma unroll
      for (int j = 0; j < 4; ++j) {
        acc[i][j] = __builtin_amdgcn_mfma_f32_16x16x32_f16(ah[i], bfr[j], acc[i][j], 0, 0, 0);
        if (HAS_LO)
          acc[i][j] = __builtin_amdgcn_mfma_f32_16x16x32_f16(al[i], bfr[j], acc[i][j], 0, 0, 0);
      }
  }

  float sc = slot_scale(slots, slotA, 1.0f) * slot_scale(slots, slotB, 1.0f);
  float lmax = 0.f;
#pragma unroll
  for (int i = 0; i < 4; ++i) {
#pragma unroll
    for (int j = 0; j < 4; ++j) {
      int gn = n0 + wn * 64 + j * 16 + l15;
      float bv = bias[gn];
#pragma unroll
      for (int r = 0; r < 4; ++r) {
        int gm = m0 + wm * 64 + i * 16 + quad * 4 + r;
        float v = acc[i][j][r] * sc + bv;
        lmax = fmaxf(lmax, fabsf(v));
        if (gn >= colLo && gn < colLo + colCount)
          out[(size_t)gm * colCount + (gn - colLo)] = v;
      }
    }
  }
  red[tid] = lmax; __syncthreads();
  for (int sh = 128; sh > 0; sh >>= 1) {
    if (tid < sh) red[tid] = fmaxf(red[tid], red[tid + sh]);
    __syncthreads();
  }
  if (tid == 0) atomicMax(&slots[absSlot], __float_as_uint(red[0]));
}

// Flash attention, f16 MFMA. Raw-domain max chain + fma-folded exp2 args,
// pkrtz-packed b32 P stores (k-permuted layout matching Vt), b128 P reads.
__global__ __launch_bounds__(256) void attn_k(const f16* __restrict__ Qh,
                                              const f16* __restrict__ Kh,
                                              const f16* __restrict__ Vt,
                                              float* __restrict__ heads,
                                              unsigned* __restrict__ slots) {
  __shared__ f16 Ks[64 * 64];
  __shared__ f16 Vs[64 * 64];
  __shared__ f16 Ph[4][16][72];   // 72-half rows: b32 stores 2-way (free), b128 reads aligned
  __shared__ f16 Pl[4][16][72];
  __shared__ float red[256];

  int tid = threadIdx.x;
  int lane = tid & 63, w = tid >> 6;
  int quad = lane >> 4, l15 = lane & 15;
  int bh = blockIdx.y, b = bh >> 4, h = bh & 15;
  int q0 = blockIdx.x * 64;

  float sq = slot_scale(slots, SLOT_Q, 0.125f);
  float sk = slot_scale(slots, SLOT_XK, 1.0f);
  float sv = slot_scale(slots, SLOT_XV, 1.0f);
  float cS = sq * sk * 1.44269504088896340736f;  // log2 domain

  const f16* qrow = Qh + ((size_t)(q0 + w * 16 + l15) * 2 + b) * 1024 + h * 64;
  half8 qf0 = *(const half8*)(qrow + quad * 8);
  half8 qf1 = *(const half8*)(qrow + 32 + quad * 8);

  int srow = lane >> 3;
  int sp = lane & 7;

  floatx4 oacc[4];
#pragma unroll
  for (int j = 0; j < 4; ++j) oacc[j] = (floatx4){0.f, 0.f, 0.f, 0.f};
  float mrow[4] = {-INFINITY, -INFINITY, -INFINITY, -INFINITY};
  float lsum[4] = {0.f, 0.f, 0.f, 0.f};

  for (int kt = 0; kt < 2048; kt += 64) {
    __syncthreads();
#pragma unroll
    for (int t = 0; t < 2; ++t) {
      int r0 = (w * 2 + t) * 8;
      int row = r0 + srow;
      int g = sp ^ (row & 7);
      gl2lds16(Kh + ((size_t)(kt + row) * 2 + b) * 1024 + h * 64 + g * 8, &Ks[r0 * 64]);
      gl2lds16(Vt + ((size_t)bh * 64 + row) * 2048 + kt + g * 8, &Vs[r0 * 64]);
    }
    __syncthreads();

    // S = Q K^T (integer-exact)
    floatx4 sacc[4];
#pragma unroll
    for (int t = 0; t < 4; ++t) {
      int row = t * 16 + l15;
      int g1 = quad ^ (row & 7);
      half8 kf0 = *(half8*)&Ks[row * 64 + g1 * 8];
      half8 kf1 = *(half8*)&Ks[row * 64 + (g1 ^ 4) * 8];
      sacc[t] = (floatx4){0.f, 0.f, 0.f, 0.f};
      sacc[t] = __builtin_amdgcn_mfma_f32_16x16x32_f16(qf0, kf0, sacc[t], 0, 0, 0);
      sacc[t] = __builtin_amdgcn_mfma_f32_16x16x32_f16(qf1, kf1, sacc[t], 0, 0, 0);
    }

    // online softmax: max chain on RAW sacc (cS>0 monotone), fma-folded exp2
    float alpha[4];
#pragma unroll
    for (int r = 0; r < 4; ++r) {
      float v0 = sacc[0][r], v1 = sacc[1][r], v2 = sacc[2][r], v3 = sacc[3][r];
      float mx = fmaxf(fmaxf(v0, v1), fmaxf(v2, v3));
      mx = fmaxf(mx, __shfl_xor(mx, 1));
      mx = fmaxf(mx, __shfl_xor(mx, 2));
      mx = fmaxf(mx, __shfl_xor(mx, 4));
      mx = fmaxf(mx, __shfl_xor(mx, 8));
      float mnew = fmaxf(mrow[r], mx);
      float msc = mnew * cS;
      float a = __builtin_amdgcn_exp2f(fmaf(mrow[r], cS, -msc));  // first tile: 0
      mrow[r] = mnew;
      float p0 = __builtin_amdgcn_exp2f(fmaf(v0, cS, -msc));
      float p1 = __builtin_amdgcn_exp2f(fmaf(v1, cS, -msc));
      float p2 = __builtin_amdgcn_exp2f(fmaf(v2, cS, -msc));
      float p3 = __builtin_amdgcn_exp2f(fmaf(v3, cS, -msc));
      lsum[r] = fmaf(lsum[r], a, p0 + p1 + p2 + p3);
      alpha[r] = a;
      int pr = quad * 4 + r;
      half2v h01 = pack2(p0, p1);
      half2v h23 = pack2(p2, p3);
      half2v l01 = pack2(p0 - (float)h01[0], p1 - (float)h01[1]);
      half2v l23 = pack2(p2 - (float)h23[0], p3 - (float)h23[1]);
      *(half2v*)&Ph[w][pr][2 * l15] = h01;
      *(half2v*)&Ph[w][pr][32 + 2 * l15] = h23;
      *(half2v*)&Pl[w][pr][2 * l15] = l01;
      *(half2v*)&Pl[w][pr][32 + 2 * l15] = l23;
    }
#pragma unroll
    for (int j = 0; j < 4; ++j)
#pragma unroll
      for (int r = 0; r < 4; ++r) oacc[j][r] *= alpha[r];

    // own-wave LDS round-trip (lgkmcnt orders it; no barrier needed)
    half8 ph0 = *(half8*)&Ph[w][l15][quad * 8];
    half8 ph1 = *(half8*)&Ph[w][l15][32 + quad * 8];
    half8 pl0 = *(half8*)&Pl[w][l15][quad * 8];
    half8 pl1 = *(half8*)&Pl[w][l15][32 + quad * 8];
#pragma unroll
    for (int j = 0; j < 4; ++j) {
      int row = j * 16 + l15;
      int g1 = quad ^ (row & 7);
      half8 vf0 = *(half8*)&Vs[row * 64 + g1 * 8];
      half8 vf1 = *(half8*)&Vs[row * 64 + (g1 ^ 4) * 8];
      oacc[j] = __builtin_amdgcn_mfma_f32_16x16x32_f16(ph0, vf0, oacc[j], 0, 0, 0);
      oacc[j] = __builtin_amdgcn_mfma_f32_16x16x32_f16(ph1, vf1, oacc[j], 0, 0, 0);
      oacc[j] = __builtin_amdgcn_mfma_f32_16x16x32_f16(pl0, vf0, oacc[j], 0, 0, 0);
      oacc[j] = __builtin_amdgcn_mfma_f32_16x16x32_f16(pl1, vf1, oacc[j], 0, 0, 0);
    }
  }

  // final l reduction across the 16 lanes of each quad
#pragma unroll
  for (int r = 0; r < 4; ++r) {
    float s = lsum[r];
    s += __shfl_xor(s, 1);
    s += __shfl_xor(s, 2);
    s += __shfl_xor(s, 4);
    s += __shfl_xor(s, 8);
    lsum[r] = s;
  }

  float lmax = 0.f;
#pragma unroll
  for (int j = 0; j < 4; ++j)
#pragma unroll
    for (int r = 0; r < 4; ++r) {
      float hv = oacc[j][r] * sv / lsum[r];
      heads[((size_t)(q0 + w * 16 + quad * 4 + r) * 2 + b) * 1024 + h * 64 + j * 16 + l15] = hv;
      lmax = fmaxf(lmax, fabsf(hv));
    }
  red[tid] = lmax; __syncthreads();
  for (int sh = 128; sh > 0; sh >>= 1) {
    if (tid < sh) red[tid] = fmaxf(red[tid], red[tid + sh]);
    __syncthreads();
  }
  if (tid == 0) atomicMax(&slots[SLOT_HD], __float_as_uint(red[0]));
}

extern "C" void kernel_launch(void* const* d_in, const int* in_sizes, int n_in,
                              void* d_out, int out_size, void* d_ws, size_t ws_size,
                              hipStream_t stream) {
  (void)in_sizes; (void)n_in; (void)out_size; (void)ws_size;
  const float* query = (const float*)d_in[0];
  const float* key   = (const float*)d_in[1];
  const float* value = (const float*)d_in[2];
  const float* Wi    = (const float*)d_in[3];
  const float* bi    = (const float*)d_in[4];
  const float* Wo    = (const float*)d_in[5];
  const float* bo    = (const float*)d_in[6];
  float* out = (float*)d_out;

  char* p = (char*)d_ws;
  unsigned* slots = (unsigned*)p;            p += 1024;
  f16* Wiq  = (f16*)p;                       p += 3072 * 1024 * 2;
  f16* Woq  = (f16*)p;                       p += 1024 * 1024 * 2;
  f16* Ahi  = (f16*)p;                       p += 4096 * 1024 * 2;
  f16* Alo  = (f16*)p;                       p += 4096 * 1024 * 2;
  float* Hd = (float*)Ahi;                   // alias (spans Ahi+Alo)
  float* Xq = (float*)p;                     p += 4096 * 1024 * 4;
  float* Y  = Xq;                            // alias: Xq dead after Qc made
  float* Xk = (float*)p;                     p += 4096 * 1024 * 4;
  f16* Qc   = (f16*)Xk;                      // alias: Xk dead after Kint
  float* Xv = (float*)p;                     p += 4096 * 1024 * 4;
  f16* Qint = (f16*)Xv;                      // alias first half: Xv dead after quantv_t
  f16* Hint = (f16*)(Xv + 2097152);          // alias second half
  f16* Kint = (f16*)p;                       p += 4096 * 1024 * 2;
  f16* Vt   = (f16*)p;                       p += 4096 * 1024 * 2;

  init_slots_k<<<1, 64, 0, stream>>>(slots);

  absmax_k<<<1024, 256, 0, stream>>>(Wi, 786432, slots, SLOT_WI);
  absmax_k<<<512, 256, 0, stream>>>(Wo, 262144, slots, SLOT_WO);
  quanti_k<<<1024, 256, 0, stream>>>(Wi, Wiq, 786432, slots, SLOT_WI, -1, 1.0f);
  quanti_k<<<512, 256, 0, stream>>>(Wo, Woq, 262144, slots, SLOT_WO, -1, 1.0f);

  dim3 g1(24, 32);  // N=3072, M=4096
  split_k<<<1024, 256, 0, stream>>>(query, Ahi, Alo, 1048576);
  gemm_mfma_k<true><<<g1, 256, 0, stream>>>(Ahi, Alo, Wiq, bi, Xq, slots, -1, SLOT_WI, SLOT_XQ,
                                            1024, 0, 1024);
  split_k<<<1024, 256, 0, stream>>>(key, Ahi, Alo, 1048576);
  gemm_mfma_k<true><<<g1, 256, 0, stream>>>(Ahi, Alo, Wiq, bi, Xk, slots, -1, SLOT_WI, SLOT_XK,
                                            1024, 1024, 1024);
  split_k<<<1024, 256, 0, stream>>>(value, Ahi, Alo, 1048576);
  gemm_mfma_k<true><<<g1, 256, 0, stream>>>(Ahi, Alo, Wiq, bi, Xv, slots, -1, SLOT_WI, SLOT_XV,
                                            1024, 2048, 1024);

  quanti_k<<<1024, 256, 0, stream>>>(Xk, Kint, 1048576, slots, SLOT_XK, -1, 1.0f);

  dim3 gvt(32, 32);
  quantv_t_k<<<gvt, 256, 0, stream>>>(Xv, Vt, slots);  // fused quant+transpose+perm

  // Q codes + absmax(Q)=s*max|code|, then /8 re-quant as pure code remap
  quanti_k<<<1024, 256, 0, stream>>>(Xq, Qc, 1048576, slots, SLOT_XQ, SLOT_Q, 1.0f);
  remapq_k<<<512, 256, 0, stream>>>(Qc, Qint, 524288, slots);

  dim3 ga(32, 32);
  attn_k<<<ga, 256, 0, stream>>>(Qint, Kint, Vt, Hd, slots);

  quanti_k<<<1024, 256, 0, stream>>>(Hd, Hint, 1048576, slots, SLOT_HD, -1, 1.0f);

  dim3 g2(8, 32);  // N=1024, M=4096
  gemm_mfma_k<false><<<g2, 256, 0, stream>>>(Hint, nullptr, Woq, bo, Y, slots,
                                             SLOT_HD, SLOT_WO, SLOT_Y, 1024, 0, 1024);

  quantf_k<<<1024, 256, 0, stream>>>(Y, out, 1048576, slots, SLOT_Y, 1.0f);
}